// Round 18
// baseline (97.953 us; speedup 1.0000x reference)
//
#include <hip/hip_runtime.h>
#include <stdint.h>

// PETNNCell collapse (proven analytically):
//   T_t == 0, m == 1;  C_new = I_t + Z_c;  h = sigmoid(X @ W_h[:, :512]^T + b_h)
//   S_new = sigmoid((1 - Z_w)*S_prev + Z_w*h + X)
//
// R18: zero-LDS, zero-barrier GEMM with K-MAJOR PACKED operands.
// R16's direct-load failure was layout (row-major frag load = 16 scattered
// lines/instr). Prepass now packs X,S,W as [kb][row][8] bf16 so a fragment
// load is 4x contiguous 256B spans (8 lines, fully coalesced = LDS-read
// efficiency, straight from L1/L2). K-loop has NO barriers, NO vmcnt, NO
// LDS: 4 independent waves/block, compiler-scheduled prefetch, acc 128 +
// frags ~50 regs -> headroom at 2 waves/SIMD. Keeps 4-output merge,
// XCD swizzle, fused epilogue (f32 X/S reads, L2-warm from A-operand).

#define BROWS 16384
#define DDIM  512

typedef __bf16 bf16x8 __attribute__((ext_vector_type(8)));
typedef __bf16 bf16x4 __attribute__((ext_vector_type(4)));
typedef float  f32x4  __attribute__((ext_vector_type(4)));

__device__ __forceinline__ float sigf(float x) { return 1.0f / (1.0f + __expf(-x)); }

__device__ __forceinline__ bf16x4 cvt4(f32x4 v) {
    bf16x4 r;
    r[0] = (__bf16)v[0]; r[1] = (__bf16)v[1];
    r[2] = (__bf16)v[2]; r[3] = (__bf16)v[3];
    return r;
}

__device__ __forceinline__ void glds16(const __bf16* g, __bf16* l) {
    __builtin_amdgcn_global_load_lds(
        (const __attribute__((address_space(1))) void*)g,
        (__attribute__((address_space(3))) void*)l, 16, 0, 0);
}

// ============ prepass: k-major bf16 pack of X, S, weights (+ T zero) ========
// ws elems: [0) Xp 8388608 ([kb 0..63][16384 rows][8])
//         | [8388608) Sp 8388608 (same)
//         | [16777216) Wp: Zc [kb 0..127][512][8] (524288)
//              | +524288 Zw (524288) | +1048576 It [kb 0..63][512][8] (262144)
//              | +1310720 Wh' (262144).  Total 18350080 elems = 36.7 MB.
__global__ __launch_bounds__(256)
void petnn_cvtK(const float* __restrict__ X,   const float* __restrict__ S,
                const float* __restrict__ Wzc, const float* __restrict__ Wzw,
                const float* __restrict__ Wit, const float* __restrict__ Wh,
                __bf16* __restrict__ ws, float* __restrict__ outT)
{
    const int i = blockIdx.x * 256 + threadIdx.x;   // one f32x4 per thread
    if (i >= 4587520) {                             // T_t == 0 exactly
        const int k = i - 4587520;                  // 0..4095
        *(f32x4*)(outT + (size_t)k * 4) = f32x4{0.f, 0.f, 0.f, 0.f};
        return;
    }
    const float* src; size_t dst;
    if (i < 2097152) {                      // X: row = i>>7, k0 = (i&127)*4
        const int row = i >> 7, k0 = (i & 127) * 4;
        src = X + (size_t)row * 512 + k0;
        dst = (size_t)(k0 >> 3) * 131072 + (size_t)row * 8 + (k0 & 7);
    } else if (i < 4194304) {
        const int j = i - 2097152;
        const int row = j >> 7, k0 = (j & 127) * 4;
        src = S + (size_t)row * 512 + k0;
        dst = 8388608 + (size_t)(k0 >> 3) * 131072 + (size_t)row * 8 + (k0 & 7);
    } else {
        const int j = i - 4194304;          // 0..393215 (weights)
        if (j < 131072) {                   // Wzc [512 cols][1024 k]
            const int col = j >> 8, k0 = (j & 255) * 4;
            src = Wzc + (size_t)col * 1024 + k0;
            dst = 16777216 + (size_t)(k0 >> 3) * 4096 + (size_t)col * 8 + (k0 & 7);
        } else if (j < 262144) {            // Wzw
            const int jj = j - 131072;
            const int col = jj >> 8, k0 = (jj & 255) * 4;
            src = Wzw + (size_t)col * 1024 + k0;
            dst = 16777216 + 524288 + (size_t)(k0 >> 3) * 4096 + (size_t)col * 8 + (k0 & 7);
        } else if (j < 327680) {            // Wit [512][512]
            const int jj = j - 262144;
            const int col = jj >> 7, k0 = (jj & 127) * 4;
            src = Wit + (size_t)col * 512 + k0;
            dst = 16777216 + 1048576 + (size_t)(k0 >> 3) * 4096 + (size_t)col * 8 + (k0 & 7);
        } else {                            // Wh cols(k) 0..511 of [512][1024]
            const int jj = j - 327680;
            const int col = jj >> 7, k0 = (jj & 127) * 4;
            src = Wh + (size_t)col * 1024 + k0;
            dst = 16777216 + 1310720 + (size_t)(k0 >> 3) * 4096 + (size_t)col * 8 + (k0 & 7);
        }
    }
    *(bf16x4*)(ws + dst) = cvt4(*(const f32x4*)src);
}

// ============ main: zero-LDS zero-barrier packed-fragment GEMM ==============
// BM=128 x BN=64, 4 outputs (Zc,Zw: K=1024, 32 tiles of BK=32; It,h: K=512,
// tiles 0..15). 256 thr = 4 independent waves; wave tile 128r x 16c x 4outs;
// acc 128/thread. NO LDS, NO barriers in the K-loop.
__global__ __launch_bounds__(256, 2)
void petnn_fusedF(const __bf16* __restrict__ ws,
                  const float* __restrict__ bzc, const float* __restrict__ bzw,
                  const float* __restrict__ bit_, const float* __restrict__ bh,
                  const float* __restrict__ X,  const float* __restrict__ S,
                  float* __restrict__ out)
{
    const int tid = threadIdx.x;
    const int bid = blockIdx.x;
    // XCD-chunked swizzle (1024 wgs, bijective; HW XCD = bid & 7), nblk-minor:
    // per XCD 16 mblk x 8 nblk; consecutive blocks share mblk -> A panel
    // L1/L2-shared between co-resident blocks.
    const int orig = (bid & 7) * 128 + (bid >> 3);
    const int nblk = orig & 7;
    const int mblk = orig >> 3;            // 0..127

    const int lane = tid & 63;
    const int wn   = tid >> 6;             // 0..3: 16-col slice of 64
    const int l15  = lane & 15;
    const int kq   = lane >> 4;            // kb sub-index 0..3

    const int arow0 = mblk * 128;
    const int ncol0 = nblk * 64;

    // ---- per-lane packed fragment bases (elements) ----
    // A: elem = kb*131072 + row*8 ; kb = kt*4 + kq ; row = arow0 + mf*16 + l15
    const __bf16* pAX = ws + (size_t)kq * 131072 + (size_t)(arow0 + l15) * 8;
    const __bf16* pAS = pAX + 8388608;
    // B: elem = kb*4096 + col*8 ; col = ncol0 + wn*16 + l15
    const size_t bl = (size_t)kq * 4096 + (size_t)(ncol0 + wn * 16 + l15) * 8;
    const __bf16* pZc = ws + 16777216 + bl;
    const __bf16* pZw = pZc + 524288;
    const __bf16* pIt = pZc + 1048576;
    const __bf16* pH  = pZc + 1310720;

    f32x4 acc[4][8] = {};    // [out][mf]

    // full tiles 0..15: A from Xp, 4 outputs
    #pragma unroll
    for (int kt = 0; kt < 16; ++kt) {
        const __bf16* ap = pAX + (size_t)kt * 524288;   // 4 planes/tile
        bf16x8 a_[8];
        #pragma unroll
        for (int mf = 0; mf < 8; ++mf)
            a_[mf] = *(const bf16x8*)(ap + mf * 128);
        const size_t wo = (size_t)kt * 16384;
        const bf16x8 b0 = *(const bf16x8*)(pZc + wo);
        const bf16x8 b1 = *(const bf16x8*)(pZw + wo);
        const bf16x8 b2 = *(const bf16x8*)(pIt + wo);
        const bf16x8 b3 = *(const bf16x8*)(pH  + wo);
        __builtin_amdgcn_s_setprio(1);
        #pragma unroll
        for (int mf = 0; mf < 8; ++mf)
            acc[0][mf] = __builtin_amdgcn_mfma_f32_16x16x32_bf16(a_[mf], b0, acc[0][mf], 0, 0, 0);
        #pragma unroll
        for (int mf = 0; mf < 8; ++mf)
            acc[1][mf] = __builtin_amdgcn_mfma_f32_16x16x32_bf16(a_[mf], b1, acc[1][mf], 0, 0, 0);
        #pragma unroll
        for (int mf = 0; mf < 8; ++mf)
            acc[2][mf] = __builtin_amdgcn_mfma_f32_16x16x32_bf16(a_[mf], b2, acc[2][mf], 0, 0, 0);
        #pragma unroll
        for (int mf = 0; mf < 8; ++mf)
            acc[3][mf] = __builtin_amdgcn_mfma_f32_16x16x32_bf16(a_[mf], b3, acc[3][mf], 0, 0, 0);
        __builtin_amdgcn_s_setprio(0);
    }
    // tail tiles 16..31: A from Sp, Zc/Zw only
    #pragma unroll
    for (int kt = 0; kt < 16; ++kt) {
        const __bf16* ap = pAS + (size_t)kt * 524288;
        bf16x8 a_[8];
        #pragma unroll
        for (int mf = 0; mf < 8; ++mf)
            a_[mf] = *(const bf16x8*)(ap + mf * 128);
        const size_t wo = (size_t)(16 + kt) * 16384;
        const bf16x8 b0 = *(const bf16x8*)(pZc + wo);
        const bf16x8 b1 = *(const bf16x8*)(pZw + wo);
        __builtin_amdgcn_s_setprio(1);
        #pragma unroll
        for (int mf = 0; mf < 8; ++mf)
            acc[0][mf] = __builtin_amdgcn_mfma_f32_16x16x32_bf16(a_[mf], b0, acc[0][mf], 0, 0, 0);
        #pragma unroll
        for (int mf = 0; mf < 8; ++mf)
            acc[1][mf] = __builtin_amdgcn_mfma_f32_16x16x32_bf16(a_[mf], b1, acc[1][mf], 0, 0, 0);
        __builtin_amdgcn_s_setprio(0);
    }

    // ---- fused epilogue (f32 X/S reads; panel is L2-warm) ----
    // C/D frag layout (m89/m91): col = lane&15, row = (lane>>4)*4 + reg
    const int col = ncol0 + wn * 16 + l15;
    const float vzc = bzc[col], vzw = bzw[col], vit = bit_[col], vh = bh[col];
    #pragma unroll
    for (int mf = 0; mf < 8; ++mf) {
        #pragma unroll
        for (int j = 0; j < 4; ++j) {
            const int row = arow0 + mf * 16 + kq * 4 + j;
            const size_t off = (size_t)row * DDIM + col;
            const float zw = sigf(acc[1][mf][j] + vzw);
            const float hh = sigf(acc[3][mf][j] + vh);
            out[off] = sigf((1.0f - zw) * S[off] + zw * hh + X[off]);  // S_new
            out[(size_t)BROWS * DDIM + off] =
                (acc[0][mf][j] + vzc) + (acc[2][mf][j] + vit);         // C_new
        }
    }
}

// ===================== fallback (ws too small): R4 path =====================
__global__ __launch_bounds__(256)
void petnn_cvtw(const float* __restrict__ Wzw, const float* __restrict__ Wh,
                const float* __restrict__ Wzc, const float* __restrict__ Wit,
                __bf16* __restrict__ wb)
{
    const int i = blockIdx.x * 256 + threadIdx.x;
    const float* src; size_t dst;
    if (i < 131072)      { src = Wzw + (size_t)i * 4;  dst = (size_t)i * 4; }
    else if (i < 196608) { const int j = i - 131072;
                           src = Wh + (size_t)(j >> 7) * 1024 + (j & 127) * 4;
                           dst = 524288 + (size_t)j * 4; }
    else if (i < 327680) { const int j = i - 196608;
                           src = Wzc + (size_t)j * 4;  dst = 786432 + (size_t)j * 4; }
    else                 { const int j = i - 327680;
                           src = Wit + (size_t)j * 4;  dst = 1310720 + (size_t)j * 4; }
    *(bf16x4*)(wb + dst) = cvt4(*(const f32x4*)src);
}

__global__ __launch_bounds__(512, 4)
void petnn_fused(const float* __restrict__ X,   const float* __restrict__ S,
                 const __bf16* __restrict__ wb,
                 const float* __restrict__ bzw, const float* __restrict__ bh,
                 const float* __restrict__ bzc, const float* __restrict__ bit_,
                 float* __restrict__ out)
{
    __shared__ __align__(16) __bf16 sA[128 * 64];
    __shared__ __align__(16) __bf16 sB[2 * 2 * 64 * 64];

    const int tid = threadIdx.x;
    const int bid = blockIdx.x;
    const int orig = (bid & 7) * 256 + (bid >> 3);
    const int fam  = orig & 1;
    const int nblk = (orig >> 1) & 7;
    const int mblk = orig >> 4;
    const int lane = tid & 63, wid = tid >> 6;
    const int wm = wid >> 2, wn = wid & 3;
    const int arow0 = mblk * 128, ncol0 = nblk * 64;
    const int srow = tid >> 4, skq = (tid & 15) << 2;
    const int bn = tid >> 3;
    const int bks = ((tid & 7) ^ (bn & 7)) << 3;
    const __bf16* wP = wb + (size_t)fam * 786432 + (size_t)(ncol0 + bn) * 1024 + bks;
    const __bf16* wQ = wb + (size_t)fam * 786432 + 524288 + (size_t)(ncol0 + bn) * 512 + bks;
    __bf16* ldsB = sB + tid * 8;

    f32x4 aP[4] = {}, aQ[4] = {};
    f32x4 ra[4];

    glds16(wP, ldsB);
    glds16(wQ, ldsB + 4096);
    #pragma unroll
    for (int p = 0; p < 4; ++p)
        ra[p] = *(const f32x4*)(X + (size_t)(arow0 + p * 32 + srow) * DDIM + skq);
    glds16(wP + 64, ldsB + 8192);
    glds16(wQ + 64, ldsB + 8192 + 4096);

    for (int kt = 0; kt < 16; ++kt) {
        const bool full = kt < 8;
        #pragma unroll
        for (int p = 0; p < 4; ++p) {
            const int r = p * 32 + srow;
            *(bf16x4*)(sA + r * 64 + (skq ^ ((r & 7) * 8))) = cvt4(ra[p]);
        }
        if (kt + 1 < 16) {
            const float* asrc = (kt + 1 < 8) ? X : S;
            const int kga = ((kt + 1) & 7) * 64 + skq;
            #pragma unroll
            for (int p = 0; p < 4; ++p)
                ra[p] = *(const f32x4*)(asrc + (size_t)(arow0 + p * 32 + srow) * DDIM + kga);
        }
        asm volatile("s_waitcnt lgkmcnt(0)" ::: "memory");
        __builtin_amdgcn_s_barrier();

        const __bf16* bb = sB + (kt & 1) * 8192;
        #pragma unroll
        for (int kk = 0; kk < 2; ++kk) {
            const int kbe = kk * 32 + (lane >> 4) * 8;
            bf16x8 af[4];
            #pragma unroll
            for (int mf = 0; mf < 4; ++mf) {
                const int r = wm * 64 + mf * 16 + (lane & 15);
                af[mf] = *(const bf16x8*)(sA + r * 64 + (kbe ^ ((r & 7) * 8)));
            }
            const int nr = wn * 16 + (lane & 15);
            const int sx = nr * 64 + (kbe ^ ((nr & 7) * 8));
            const bf16x8 bP = *(const bf16x8*)(bb + sx);
            #pragma unroll
            for (int mf = 0; mf < 4; ++mf)
                aP[mf] = __builtin_amdgcn_mfma_f32_16x16x32_bf16(af[mf], bP, aP[mf], 0, 0, 0);
            if (full) {
                const bf16x8 bQ = *(const bf16x8*)(bb + 4096 + sx);
                #pragma unroll
                for (int mf = 0; mf < 4; ++mf)
                    aQ[mf] = __builtin_amdgcn_mfma_f32_16x16x32_bf16(af[mf], bQ, aQ[mf], 0, 0, 0);
            }
        }

        if (kt + 1 < 16) {
            asm volatile("" ::: "memory");
            __builtin_amdgcn_s_barrier();
            asm volatile("" ::: "memory");
            if (kt + 2 < 16) {
                __bf16* bd = sB + (kt & 1) * 8192 + tid * 8;
                glds16(wP + (size_t)(kt + 2) * 64, bd);
                if (kt + 2 < 8) glds16(wQ + (size_t)(kt + 2) * 64, bd + 4096);
            }
        }
    }

    const int col  = ncol0 + wn * 16 + (lane & 15);
    const int rowb = arow0 + wm * 64;
    if (fam == 0) {
        const float vzw = bzw[col], vh = bh[col];
        #pragma unroll
        for (int mf = 0; mf < 4; ++mf) {
            #pragma unroll
            for (int j = 0; j < 4; ++j) {
                const int row = rowb + mf * 16 + ((lane >> 4) << 2) + j;
                const size_t off = (size_t)row * DDIM + col;
                const float zw = sigf(aP[mf][j] + vzw);
                const float hh = sigf(aQ[mf][j] + vh);
                out[off] = sigf((1.0f - zw) * S[off] + zw * hh + X[off]);
            }
        }
    } else {
        const float vzc = bzc[col], vit = bit_[col];
        #pragma unroll
        for (int mf = 0; mf < 4; ++mf) {
            #pragma unroll
            for (int j = 0; j < 4; ++j) {
                const int row = rowb + mf * 16 + ((lane >> 4) << 2) + j;
                const size_t off = (size_t)row * DDIM + col;
                out[(size_t)BROWS * DDIM + off] =
                    (aP[mf][j] + vzc) + (aQ[mf][j] + vit);
            }
        }
    }
}

__global__ void petnn_zeroT(float* __restrict__ t) {
    t[blockIdx.x * 256 + threadIdx.x] = 0.0f;
}

extern "C" void kernel_launch(void* const* d_in, const int* in_sizes, int n_in,
                              void* d_out, int out_size, void* d_ws, size_t ws_size,
                              hipStream_t stream) {
    (void)in_sizes; (void)n_in; (void)out_size;
    const float* X    = (const float*)d_in[0];
    const float* S    = (const float*)d_in[1];
    const float* Wzc  = (const float*)d_in[6];
    const float* bzc  = (const float*)d_in[7];
    const float* Wzw  = (const float*)d_in[8];
    const float* bzw  = (const float*)d_in[9];
    const float* Wit  = (const float*)d_in[10];
    const float* bit_ = (const float*)d_in[11];
    const float* Wh   = (const float*)d_in[14];
    const float* bh   = (const float*)d_in[15];
    float* out = (float*)d_out;

    if (ws_size >= 36700160u) {
        __bf16* ws = (__bf16*)d_ws;
        petnn_cvtK<<<dim3(17936), dim3(256), 0, stream>>>(
            X, S, Wzc, Wzw, Wit, Wh, ws, out + 2 * (size_t)BROWS * DDIM);
        petnn_fusedF<<<dim3(1024), dim3(256), 0, stream>>>(
            ws, bzc, bzw, bit_, bh, X, S, out);
    } else {
        __bf16* wb = (__bf16*)d_ws;
        petnn_cvtw<<<dim3(1536), dim3(256), 0, stream>>>(Wzw, Wh, Wzc, Wit, wb);
        petnn_fused<<<dim3(2048), dim3(512), 0, stream>>>(
            X, S, wb, bzw, bh, bzc, bit_, out);
        petnn_zeroT<<<dim3(64), dim3(256), 0, stream>>>(out + 2 * (size_t)BROWS * DDIM);
    }
}

// Round 19
// 85.965 us; speedup vs baseline: 1.1395x; 1.1395x over previous
//
#include <hip/hip_runtime.h>
#include <stdint.h>

// PETNNCell collapse (proven analytically):
//   T_t == 0, m == 1;  C_new = I_t + Z_c;  h = sigmoid(X @ W_h[:, :512]^T + b_h)
//   S_new = sigmoid((1 - Z_w)*S_prev + Z_w*h + X)
//
// R19 = R15 restored (measured best: 86.09 us total, main 76.5 us).
// Rationale: R14/R15 (LDS-staged) and R18 (zero-LDS zero-barrier packed)
// converge to the same 75-77 us / ~27% MfmaUtil -> the limiter is the
// per-SIMD vmem+MFMA issue stream at this shallow K (1024/512), not any
// sync/LDS/occupancy structure. R18's k-major prepass scatters writes and
// regresses total; R15's contiguous prepass is optimal. Locking in R15.

#define BROWS 16384
#define DDIM  512

typedef __bf16 bf16x8 __attribute__((ext_vector_type(8)));
typedef __bf16 bf16x4 __attribute__((ext_vector_type(4)));
typedef float  f32x4  __attribute__((ext_vector_type(4)));

__device__ __forceinline__ float sigf(float x) { return 1.0f / (1.0f + __expf(-x)); }

__device__ __forceinline__ bf16x4 cvt4(f32x4 v) {
    bf16x4 r;
    r[0] = (__bf16)v[0]; r[1] = (__bf16)v[1];
    r[2] = (__bf16)v[2]; r[3] = (__bf16)v[3];
    return r;
}

__device__ __forceinline__ void glds16(const __bf16* g, __bf16* l) {
    __builtin_amdgcn_global_load_lds(
        (const __attribute__((address_space(1))) void*)g,
        (__attribute__((address_space(3))) void*)l, 16, 0, 0);
}

#define BAR   __builtin_amdgcn_s_barrier()
#define VM0   asm volatile("s_waitcnt vmcnt(0)" ::: "memory")
#define MEMF  asm volatile("" ::: "memory")

// ===================== prepass: X, S, weights -> bf16 (+ T_t zero) ==========
// ws elems: [0) Xb 8388608 | [8388608) Sb 8388608 | [16777216) weights:
//   +0 Wzc 512x1024 | +524288 Wzw 512x1024 | +1048576 Wit 512x512
//   | +1310720 Wh' 512x512 (cols 0..511). Total 18350080 elems = 36.7 MB.
__global__ __launch_bounds__(256)
void petnn_cvt(const float* __restrict__ X,   const float* __restrict__ S,
               const float* __restrict__ Wzc, const float* __restrict__ Wzw,
               const float* __restrict__ Wit, const float* __restrict__ Wh,
               __bf16* __restrict__ ws, float* __restrict__ outT)
{
    const int i = blockIdx.x * 256 + threadIdx.x;   // f32x4 chunk
    if (i >= 4587520) {                             // T_t == 0 exactly
        const int k = i - 4587520;                  // 0..4095
        *(f32x4*)(outT + (size_t)k * 4) = f32x4{0.f, 0.f, 0.f, 0.f};
        return;
    }
    const float* src; size_t dst;
    if (i < 2097152)      { src = X + (size_t)i * 4; dst = (size_t)i * 4; }
    else if (i < 4194304) { const int j = i - 2097152;
                            src = S + (size_t)j * 4; dst = 8388608 + (size_t)j * 4; }
    else {
        const int j = i - 4194304;                  // 0..393215 (weights)
        if (j < 131072)      { src = Wzc + (size_t)j * 4;
                               dst = 16777216 + (size_t)j * 4; }
        else if (j < 262144) { const int jj = j - 131072;
                               src = Wzw + (size_t)jj * 4;
                               dst = 16777216 + 524288 + (size_t)jj * 4; }
        else if (j < 327680) { const int jj = j - 262144;
                               src = Wit + (size_t)jj * 4;
                               dst = 16777216 + 1048576 + (size_t)jj * 4; }
        else                 { const int jj = j - 327680;   // Wh cols 0..511
                               src = Wh + (size_t)(jj >> 7) * 1024 + (jj & 127) * 4;
                               dst = 16777216 + 1310720 + (size_t)jj * 4; }
    }
    *(bf16x4*)(ws + dst) = cvt4(*(const f32x4*)src);
}

// ===================== main: BK=64 4-output fused GEMM ======================
// BM=256 x BN=64, 4 outputs. Zc,Zw: K=1024 -> tiles 0..15 (0..7 X, 8..15 S);
// It,h: K=512 -> tiles 0..7 only. 512 thr = 8 waves 4(M) x 2(N); wave tile
// 64x32 x 4outs; acc 128/thread. LDS: 2 slots x (A 32K + B 32K) = 128 KiB.
__global__ __launch_bounds__(512, 2)
void petnn_fusedC(const __bf16* __restrict__ Xb, const __bf16* __restrict__ Sb,
                  const __bf16* __restrict__ wb,
                  const float* __restrict__ bzc, const float* __restrict__ bzw,
                  const float* __restrict__ bit_, const float* __restrict__ bh,
                  float* __restrict__ out)
{
    __shared__ __align__(16) __bf16 sA[2 * 16384];  // [slot][256r][64k] 64 KiB
    __shared__ __align__(16) __bf16 sB[2 * 16384];  // [slot][4o][64c][64k] 64 KiB

    const int tid = threadIdx.x;
    const int bid = blockIdx.x;
    // XCD-chunked swizzle (512 wgs, bijective; HW XCD = bid & 7), nblk-minor:
    // per XCD 8 mblk x 8 nblk -> each A tile fetched once per XCD's L2.
    const int orig = (bid & 7) * 64 + (bid >> 3);
    const int nblk = orig & 7;
    const int mblk = orig >> 3;            // 0..63

    const int lane = tid & 63, wid = tid >> 6;
    const int wm = wid >> 1;               // 0..3 (64-row slice of 256)
    const int wn = wid & 1;                // 0..1 (32-col slice of 64)
    const int l15 = lane & 15;
    const int kc  = lane >> 4;             // frag k-chunk 0..3

    const int arow0 = mblk * 256;
    const int ncol0 = nblk * 64;

    // ---- staging sources (XOR swizzle in GLOBAL addr; LDS dest linear) ----
    const int gr   = tid >> 3;                       // 0..63
    const int aswz = ((tid & 7) ^ (gr & 7)) * 8;
    const __bf16* pXA = Xb + (size_t)(arow0 + gr) * 512 + aswz;
    const __bf16* pSA = Sb + (size_t)(arow0 + gr) * 512 + aswz;
    const __bf16* pZc = wb +       0 + (size_t)(ncol0 + gr) * 1024 + aswz;  // K=1024
    const __bf16* pZw = wb +  524288 + (size_t)(ncol0 + gr) * 1024 + aswz;  // K=1024
    const __bf16* pIt = wb + 1048576 + (size_t)(ncol0 + gr) * 512  + aswz;  // K=512
    const __bf16* pH  = wb + 1310720 + (size_t)(ncol0 + gr) * 512  + aswz;  // K=512

    // ---- fragment read offsets (elems within one 16384-elem slot) ----
    int aoff[2][4], boff[2][2];
    #pragma unroll
    for (int mf = 0; mf < 4; ++mf) {
        const int r = wm * 64 + mf * 16 + l15;
        aoff[0][mf] = r * 64 + (((kc)     ^ (r & 7)) * 8);
        aoff[1][mf] = r * 64 + (((4 + kc) ^ (r & 7)) * 8);
    }
    #pragma unroll
    for (int nf = 0; nf < 2; ++nf) {
        const int c = wn * 32 + nf * 16 + l15;
        boff[0][nf] = c * 64 + (((kc)     ^ (c & 7)) * 8);
        boff[1][nf] = c * 64 + (((4 + kc) ^ (c & 7)) * 8);
    }

    f32x4 acc[4][4][2] = {};    // [out][mf][nf]

#define ISSUE_FULL(T) { \
        const __bf16* a_ = (((T) < 8) ? pXA : pSA) + ((T) & 7) * 64; \
        __bf16* dA_ = sA + ((T) & 1) * 16384 + tid * 8; \
        glds16(a_,         dA_); \
        glds16(a_ + 32768, dA_ + 4096); \
        glds16(a_ + 65536, dA_ + 8192); \
        glds16(a_ + 98304, dA_ + 12288); \
        __bf16* dB_ = sB + ((T) & 1) * 16384 + tid * 8; \
        glds16(pZc + (T) * 64, dB_); \
        glds16(pZw + (T) * 64, dB_ + 4096); \
        glds16(pIt + (T) * 64, dB_ + 8192); \
        glds16(pH  + (T) * 64, dB_ + 12288); }

#define ISSUE_TAIL(T) { \
        const __bf16* a_ = pSA + ((T) & 7) * 64; \
        __bf16* dA_ = sA + ((T) & 1) * 16384 + tid * 8; \
        glds16(a_,         dA_); \
        glds16(a_ + 32768, dA_ + 4096); \
        glds16(a_ + 65536, dA_ + 8192); \
        glds16(a_ + 98304, dA_ + 12288); \
        __bf16* dB_ = sB + ((T) & 1) * 16384 + tid * 8; \
        glds16(pZc + (T) * 64, dB_); \
        glds16(pZw + (T) * 64, dB_ + 4096); }

#define BODY(T, NOUT) { \
        const __bf16* aS_ = sA + ((T) & 1) * 16384; \
        const __bf16* bS_ = sB + ((T) & 1) * 16384; \
        bf16x8 a_[2][4]; \
        _Pragma("unroll") \
        for (int kk = 0; kk < 2; ++kk) \
            _Pragma("unroll") \
            for (int mf = 0; mf < 4; ++mf) \
                a_[kk][mf] = *(const bf16x8*)(aS_ + aoff[kk][mf]); \
        __builtin_amdgcn_s_setprio(1); \
        _Pragma("unroll") \
        for (int o = 0; o < (NOUT); ++o) { \
            bf16x8 b_[2][2]; \
            _Pragma("unroll") \
            for (int kk = 0; kk < 2; ++kk) \
                _Pragma("unroll") \
                for (int nf = 0; nf < 2; ++nf) \
                    b_[kk][nf] = *(const bf16x8*)(bS_ + o * 4096 + boff[kk][nf]); \
            _Pragma("unroll") \
            for (int kk = 0; kk < 2; ++kk) \
                _Pragma("unroll") \
                for (int nf = 0; nf < 2; ++nf) \
                    _Pragma("unroll") \
                    for (int mf = 0; mf < 4; ++mf) \
                        acc[o][mf][nf] = __builtin_amdgcn_mfma_f32_16x16x32_bf16( \
                            a_[kk][mf], b_[kk][nf], acc[o][mf][nf], 0, 0, 0); \
        } \
        __builtin_amdgcn_s_setprio(0); }

    // ---- pipeline: single barrier per tile, depth-1 prefetch ----
    ISSUE_FULL(0)
    for (int kt = 0; kt < 8; ++kt) {
        VM0; MEMF; BAR; MEMF;
        if (kt < 7)       { ISSUE_FULL(kt + 1) }
        else              { ISSUE_TAIL(8) }
        MEMF;
        BODY(kt, 4)
    }
    for (int kt = 8; kt < 16; ++kt) {
        VM0; MEMF; BAR; MEMF;
        if (kt < 15)      { ISSUE_TAIL(kt + 1) }
        MEMF;
        BODY(kt, 2)
    }

#undef ISSUE_FULL
#undef ISSUE_TAIL
#undef BODY

    // ---- fused epilogue (bf16 Xb/Sb reads) ----
    // C/D frag layout (m89/m91): col = lane&15, row = (lane>>4)*4 + reg
    const int rowb = arow0 + wm * 64;
    #pragma unroll
    for (int nf = 0; nf < 2; ++nf) {
        const int col = ncol0 + wn * 32 + nf * 16 + l15;
        const float vzc = bzc[col], vzw = bzw[col], vit = bit_[col], vh = bh[col];
        #pragma unroll
        for (int mf = 0; mf < 4; ++mf) {
            #pragma unroll
            for (int j = 0; j < 4; ++j) {
                const int row = rowb + mf * 16 + (lane >> 4) * 4 + j;
                const size_t off = (size_t)row * DDIM + col;
                const float zw = sigf(acc[1][mf][nf][j] + vzw);
                const float hh = sigf(acc[3][mf][nf][j] + vh);
                out[off] = sigf((1.0f - zw) * (float)Sb[off] + zw * hh
                                + (float)Xb[off]);                         // S_new
                out[(size_t)BROWS * DDIM + off] =
                    (acc[0][mf][nf][j] + vzc) + (acc[2][mf][nf][j] + vit); // C_new
            }
        }
    }
}

// ===================== fallback (ws too small): R4 path =====================
__global__ __launch_bounds__(256)
void petnn_cvtw(const float* __restrict__ Wzw, const float* __restrict__ Wh,
                const float* __restrict__ Wzc, const float* __restrict__ Wit,
                __bf16* __restrict__ wb)
{
    const int i = blockIdx.x * 256 + threadIdx.x;
    const float* src; size_t dst;
    if (i < 131072)      { src = Wzw + (size_t)i * 4;  dst = (size_t)i * 4; }
    else if (i < 196608) { const int j = i - 131072;
                           src = Wh + (size_t)(j >> 7) * 1024 + (j & 127) * 4;
                           dst = 524288 + (size_t)j * 4; }
    else if (i < 327680) { const int j = i - 196608;
                           src = Wzc + (size_t)j * 4;  dst = 786432 + (size_t)j * 4; }
    else                 { const int j = i - 327680;
                           src = Wit + (size_t)j * 4;  dst = 1310720 + (size_t)j * 4; }
    *(bf16x4*)(wb + dst) = cvt4(*(const f32x4*)src);
}

__global__ __launch_bounds__(512, 4)
void petnn_fused(const float* __restrict__ X,   const float* __restrict__ S,
                 const __bf16* __restrict__ wb,
                 const float* __restrict__ bzw, const float* __restrict__ bh,
                 const float* __restrict__ bzc, const float* __restrict__ bit_,
                 float* __restrict__ out)
{
    __shared__ __align__(16) __bf16 sA[128 * 64];
    __shared__ __align__(16) __bf16 sB[2 * 2 * 64 * 64];

    const int tid = threadIdx.x;
    const int bid = blockIdx.x;
    const int orig = (bid & 7) * 256 + (bid >> 3);
    const int fam  = orig & 1;
    const int nblk = (orig >> 1) & 7;
    const int mblk = orig >> 4;
    const int lane = tid & 63, wid = tid >> 6;
    const int wm = wid >> 2, wn = wid & 3;
    const int arow0 = mblk * 128, ncol0 = nblk * 64;
    const int srow = tid >> 4, skq = (tid & 15) << 2;
    const int bn = tid >> 3;
    const int bks = ((tid & 7) ^ (bn & 7)) << 3;
    const __bf16* wP = wb + (size_t)fam * 786432 + (size_t)(ncol0 + bn) * 1024 + bks;
    const __bf16* wQ = wb + (size_t)fam * 786432 + 524288 + (size_t)(ncol0 + bn) * 512 + bks;
    __bf16* ldsB = sB + tid * 8;

    f32x4 aP[4] = {}, aQ[4] = {};
    f32x4 ra[4];

    glds16(wP, ldsB);
    glds16(wQ, ldsB + 4096);
    #pragma unroll
    for (int p = 0; p < 4; ++p)
        ra[p] = *(const f32x4*)(X + (size_t)(arow0 + p * 32 + srow) * DDIM + skq);
    glds16(wP + 64, ldsB + 8192);
    glds16(wQ + 64, ldsB + 8192 + 4096);

    for (int kt = 0; kt < 16; ++kt) {
        const bool full = kt < 8;
        #pragma unroll
        for (int p = 0; p < 4; ++p) {
            const int r = p * 32 + srow;
            *(bf16x4*)(sA + r * 64 + (skq ^ ((r & 7) * 8))) = cvt4(ra[p]);
        }
        if (kt + 1 < 16) {
            const float* asrc = (kt + 1 < 8) ? X : S;
            const int kga = ((kt + 1) & 7) * 64 + skq;
            #pragma unroll
            for (int p = 0; p < 4; ++p)
                ra[p] = *(const f32x4*)(asrc + (size_t)(arow0 + p * 32 + srow) * DDIM + kga);
        }
        asm volatile("s_waitcnt lgkmcnt(0)" ::: "memory");
        __builtin_amdgcn_s_barrier();

        const __bf16* bb = sB + (kt & 1) * 8192;
        #pragma unroll
        for (int kk = 0; kk < 2; ++kk) {
            const int kbe = kk * 32 + (lane >> 4) * 8;
            bf16x8 af[4];
            #pragma unroll
            for (int mf = 0; mf < 4; ++mf) {
                const int r = wm * 64 + mf * 16 + (lane & 15);
                af[mf] = *(const bf16x8*)(sA + r * 64 + (kbe ^ ((r & 7) * 8)));
            }
            const int nr = wn * 16 + (lane & 15);
            const int sx = nr * 64 + (kbe ^ ((nr & 7) * 8));
            const bf16x8 bP = *(const bf16x8*)(bb + sx);
            #pragma unroll
            for (int mf = 0; mf < 4; ++mf)
                aP[mf] = __builtin_amdgcn_mfma_f32_16x16x32_bf16(af[mf], bP, aP[mf], 0, 0, 0);
            if (full) {
                const bf16x8 bQ = *(const bf16x8*)(bb + 4096 + sx);
                #pragma unroll
                for (int mf = 0; mf < 4; ++mf)
                    aQ[mf] = __builtin_amdgcn_mfma_f32_16x16x32_bf16(af[mf], bQ, aQ[mf], 0, 0, 0);
            }
        }

        if (kt + 1 < 16) {
            asm volatile("" ::: "memory");
            __builtin_amdgcn_s_barrier();
            asm volatile("" ::: "memory");
            if (kt + 2 < 16) {
                __bf16* bd = sB + (kt & 1) * 8192 + tid * 8;
                glds16(wP + (size_t)(kt + 2) * 64, bd);
                if (kt + 2 < 8) glds16(wQ + (size_t)(kt + 2) * 64, bd + 4096);
            }
        }
    }

    const int col  = ncol0 + wn * 16 + (lane & 15);
    const int rowb = arow0 + wm * 64;
    if (fam == 0) {
        const float vzw = bzw[col], vh = bh[col];
        #pragma unroll
        for (int mf = 0; mf < 4; ++mf) {
            #pragma unroll
            for (int j = 0; j < 4; ++j) {
                const int row = rowb + mf * 16 + ((lane >> 4) << 2) + j;
                const size_t off = (size_t)row * DDIM + col;
                const float zw = sigf(aP[mf][j] + vzw);
                const float hh = sigf(aQ[mf][j] + vh);
                out[off] = sigf((1.0f - zw) * S[off] + zw * hh + X[off]);
            }
        }
    } else {
        const float vzc = bzc[col], vit = bit_[col];
        #pragma unroll
        for (int mf = 0; mf < 4; ++mf) {
            #pragma unroll
            for (int j = 0; j < 4; ++j) {
                const int row = rowb + mf * 16 + ((lane >> 4) << 2) + j;
                const size_t off = (size_t)row * DDIM + col;
                out[(size_t)BROWS * DDIM + off] =
                    (aP[mf][j] + vzc) + (aQ[mf][j] + vit);
            }
        }
    }
}

__global__ void petnn_zeroT(float* __restrict__ t) {
    t[blockIdx.x * 256 + threadIdx.x] = 0.0f;
}

extern "C" void kernel_launch(void* const* d_in, const int* in_sizes, int n_in,
                              void* d_out, int out_size, void* d_ws, size_t ws_size,
                              hipStream_t stream) {
    (void)in_sizes; (void)n_in; (void)out_size;
    const float* X    = (const float*)d_in[0];
    const float* S    = (const float*)d_in[1];
    const float* Wzc  = (const float*)d_in[6];
    const float* bzc  = (const float*)d_in[7];
    const float* Wzw  = (const float*)d_in[8];
    const float* bzw  = (const float*)d_in[9];
    const float* Wit  = (const float*)d_in[10];
    const float* bit_ = (const float*)d_in[11];
    const float* Wh   = (const float*)d_in[14];
    const float* bh   = (const float*)d_in[15];
    float* out = (float*)d_out;

    if (ws_size >= 36700160u) {
        __bf16* ws = (__bf16*)d_ws;
        const __bf16* Xb = ws;
        const __bf16* Sb = ws + 8388608;
        const __bf16* wb = ws + 16777216;
        petnn_cvt<<<dim3(17936), dim3(256), 0, stream>>>(
            X, S, Wzc, Wzw, Wit, Wh, ws, out + 2 * (size_t)BROWS * DDIM);
        petnn_fusedC<<<dim3(512), dim3(512), 0, stream>>>(
            Xb, Sb, wb, bzc, bzw, bit_, bh, out);
    } else {
        __bf16* wb = (__bf16*)d_ws;
        petnn_cvtw<<<dim3(1536), dim3(256), 0, stream>>>(Wzw, Wh, Wzc, Wit, wb);
        petnn_fused<<<dim3(2048), dim3(512), 0, stream>>>(
            X, S, wb, bzw, bh, bzc, bit_, out);
        petnn_zeroT<<<dim3(64), dim3(256), 0, stream>>>(out + 2 * (size_t)BROWS * DDIM);
    }
}